// Round 8
// baseline (159.381 us; speedup 1.0000x reference)
//
#include <hip/hip_runtime.h>
#include <cstdint>
#include <cstddef>

// Problem constants
#define B_DIM 4096   // batch (GEMM M)
#define S_DIM 2048   // states (GEMM N)
#define D_DIM 2496   // feature dim (GEMM K) = 39 * 64
#define QSCALE 127.0f
#define QSCALE2 16129.0f   // 127^2
#define KITERS (D_DIM / 64)  // 39 k-steps of 64 bytes

// R8: LDS ELIMINATED. R3 (occupancy x2 = no change), R6 (dbuf = regression),
// R7 (barriers/3 = -3us) proved the 2-barrier stage/drain/compute structure
// is the wall (~40% of cycles with all pipes idle). The i8 16x16x64 fragment
// is 16 B/lane at (row+fr)*K + t*64 + (lane>>4)*16 -> load it DIRECTLY
// global->VGPR with global_load_dwordx4, software-pipelined 2 deep.
// No __syncthreads, no vmcnt(0) drain; compiler emits fine-grained
// s_waitcnt vmcnt(N) (the AITER-style interleave). L1/L2 serve the reuse
// the LDS used to (2x2 wave arrangement keeps 2-way row sharing in-block).
#define BM 128
#define BN 128

typedef __attribute__((ext_vector_type(4))) int int4v;

// ---------------------------------------------------------------------------
struct __attribute__((aligned(8))) uc8 { unsigned char c[8]; };

// Prep, wave-per-row: quantize one row to u8 in [0,127] (RTN) and compute the
// EXACT fp32 squared norm of the original floats via shuffle reduce.
__global__ __launch_bounds__(256) void prep_kernel(
    const float* __restrict__ X, const float* __restrict__ Mx,
    unsigned char* __restrict__ Xq, unsigned char* __restrict__ Mq,
    float* __restrict__ xsq, float* __restrict__ msq)
{
    const int lane = threadIdx.x & 63;
    const int row  = blockIdx.x * 4 + (threadIdx.x >> 6);

    const float* src; unsigned char* dst; float* sq;
    if (row < B_DIM) {
        src = X + (size_t)row * D_DIM; dst = Xq + (size_t)row * D_DIM; sq = xsq + row;
    } else {
        const int r = row - B_DIM;
        src = Mx + (size_t)r * D_DIM; dst = Mq + (size_t)r * D_DIM; sq = msq + r;
    }

    const float4* s4 = (const float4*)src;
    uc8* d8 = (uc8*)dst;
    float acc = 0.f;
    for (int i = lane; i < D_DIM / 8; i += 64) {
        float4 a = s4[2 * i], b = s4[2 * i + 1];
        acc += a.x * a.x + a.y * a.y + a.z * a.z + a.w * a.w;
        acc += b.x * b.x + b.y * b.y + b.z * b.z + b.w * b.w;
        uc8 q;
        q.c[0] = (unsigned char)__float2int_rn(a.x * QSCALE);
        q.c[1] = (unsigned char)__float2int_rn(a.y * QSCALE);
        q.c[2] = (unsigned char)__float2int_rn(a.z * QSCALE);
        q.c[3] = (unsigned char)__float2int_rn(a.w * QSCALE);
        q.c[4] = (unsigned char)__float2int_rn(b.x * QSCALE);
        q.c[5] = (unsigned char)__float2int_rn(b.y * QSCALE);
        q.c[6] = (unsigned char)__float2int_rn(b.z * QSCALE);
        q.c[7] = (unsigned char)__float2int_rn(b.w * QSCALE);
        d8[i] = q;
    }
    #pragma unroll
    for (int off = 32; off > 0; off >>= 1)
        acc += __shfl_down(acc, off, 64);
    if (lane == 0) *sq = acc;
}

// ---------------------------------------------------------------------------
// C[row,col] = (2*cross - xsq[row] - msq[col]) / 500, cross = acc_i32/127^2.
// A: [4096, 2496] u8 row-major; Bt: [2048, 2496] u8 row-major (NT GEMM).
__global__ __launch_bounds__(256, 2) void gemm_kernel(
    const unsigned char* __restrict__ A,
    const unsigned char* __restrict__ Bt,
    const float* __restrict__ xsq, const float* __restrict__ msq,
    float* __restrict__ C)
{
    constexpr int N = S_DIM;
    constexpr int K = D_DIM;   // bytes per row

    const int lane = threadIdx.x & 63;
    const int wave = threadIdx.x >> 6;   // 4 waves, 2x2 of 64x64 tiles
    const int wm = wave >> 1;
    const int wn = wave & 1;
    const int bm = blockIdx.y;
    const int bn = blockIdx.x;

    // i8 16x16x64 A/B fragment (R5-verified): m (or n) = lane&15,
    // k-byte = (lane>>4)*16 + j. Per-lane global base for each of the
    // 4 m-subtiles / 4 n-subtiles; advance by 64 per k-step.
    const int fr = lane & 15;
    const int ko = (lane >> 4) * 16;

    const unsigned char* pA[4];
    const unsigned char* pB[4];
    #pragma unroll
    for (int i = 0; i < 4; ++i) {
        pA[i] = A  + (size_t)(bm * BM + wm * 64 + i * 16 + fr) * K + ko;
        pB[i] = Bt + (size_t)(bn * BN + wn * 64 + i * 16 + fr) * K + ko;
    }

    int4v acc[4][4] = {};
    int4v a0[4], b0[4], a1[4], b1[4];

#define LOAD_STEP(av, bv, kb)                                              \
    do {                                                                   \
        _Pragma("unroll")                                                  \
        for (int i = 0; i < 4; ++i) {                                      \
            av[i] = *(const int4v*)(pA[i] + (kb));                         \
            bv[i] = *(const int4v*)(pB[i] + (kb));                         \
        }                                                                  \
    } while (0)

#define MFMA_STEP(av, bv)                                                  \
    do {                                                                   \
        _Pragma("unroll")                                                  \
        for (int mi = 0; mi < 4; ++mi)                                     \
            _Pragma("unroll")                                              \
            for (int ni = 0; ni < 4; ++ni)                                 \
                acc[mi][ni] = __builtin_amdgcn_mfma_i32_16x16x64_i8(       \
                    av[mi], bv[ni], acc[mi][ni], 0, 0, 0);                 \
    } while (0)

    // Software pipeline, 2 stages in registers, no barriers anywhere.
    LOAD_STEP(a0, b0, 0);
    int t = 0;
    for (; t + 2 < KITERS; t += 2) {       // t = 0,2,...,36
        LOAD_STEP(a1, b1, (t + 1) * 64);
        MFMA_STEP(a0, b0);
        LOAD_STEP(a0, b0, (t + 2) * 64);
        MFMA_STEP(a1, b1);
    }
    // KITERS = 39 (odd): after the loop t = 38 and a0/b0 hold step 38.
    MFMA_STEP(a0, b0);

#undef LOAD_STEP
#undef MFMA_STEP

    // Epilogue. C/D layout dtype-independent (m121-m128): col = lane&15,
    // row = (lane>>4)*4 + reg. cross = acc/127^2 in fp32.
    const int row0 = bm * BM + wm * 64 + (lane >> 4) * 4;
    const int col0 = bn * BN + wn * 64 + fr;
    float ms[4];
    #pragma unroll
    for (int ni = 0; ni < 4; ++ni) ms[ni] = msq[col0 + ni * 16];
    #pragma unroll
    for (int mi = 0; mi < 4; ++mi) {
        #pragma unroll
        for (int r = 0; r < 4; ++r) {
            const int row = row0 + mi * 16 + r;
            const float xs = xsq[row];
            #pragma unroll
            for (int ni = 0; ni < 4; ++ni) {
                const float cr2 = (float)acc[mi][ni][r] * (2.0f / QSCALE2);
                const float v = (cr2 - xs - ms[ni]) * (1.0f / 500.0f);
                C[(size_t)row * N + col0 + ni * 16] = v;
            }
        }
    }
}

// ---------------------------------------------------------------------------
extern "C" void kernel_launch(void* const* d_in, const int* in_sizes, int n_in,
                              void* d_out, int out_size, void* d_ws, size_t ws_size,
                              hipStream_t stream) {
    const float* X  = (const float*)d_in[0];  // [4096, 2496]
    const float* Mx = (const float*)d_in[1];  // [2048, 2496]
    float* out = (float*)d_out;               // [4096, 2048]

    // Workspace layout (~15.4 MB): Xq u8 | Mq u8 | xsq f32 | msq f32
    unsigned char* Xq = (unsigned char*)d_ws;
    unsigned char* Mq = Xq + (size_t)B_DIM * D_DIM;
    float* xsq = (float*)(Mq + (size_t)S_DIM * D_DIM);
    float* msq = xsq + B_DIM;

    prep_kernel<<<(B_DIM + S_DIM) / 4, 256, 0, stream>>>(X, Mx, Xq, Mq, xsq, msq);

    dim3 grid(S_DIM / BN, B_DIM / BM);  // (16, 32) = 512 blocks -> 2/CU
    gemm_kernel<<<grid, 256, 0, stream>>>(Xq, Mq, xsq, msq, out);
}

// Round 9
// 138.256 us; speedup vs baseline: 1.1528x; 1.1528x over previous
//
#include <hip/hip_runtime.h>
#include <cstdint>
#include <cstddef>

// Problem constants
#define B_DIM 4096   // batch (GEMM M)
#define S_DIM 2048   // states (GEMM N)
#define D_DIM 2496   // feature dim (GEMM K) = 13 * 192
#define QSCALE 127.0f
#define QSCALE2 16129.0f   // 127^2
#define BK 192
#define KITERS (D_DIM / BK)   // 13

// R9: 64x128 blocks of 128 threads (2 waves of 64x64), BK=192, i8 MFMA.
// R7 ledger: per CU/iter LDS 3080 + VMEM 1750 + MFMA 1960 on different pipes,
// measured 6794 -> ~50% overlap. With only 2 blocks/CU the barrier phase
// alternation can't interleave. This tile gives grid=1024 -> 4 blocks/CU
// (LDS 36 KB x4 = 144 <= 160 KB), same per-wave economics, 4-way phase
// interleave. R8's direct-global reverted (latency-bound, MfmaUtil 11%).
#define BM 64
#define BN 128

typedef __attribute__((ext_vector_type(4))) int int4v;

// ---------------------------------------------------------------------------
struct __attribute__((aligned(8))) uc8 { unsigned char c[8]; };

// Prep, wave-per-row: quantize one row to u8 in [0,127] (RTN) and compute the
// EXACT fp32 squared norm of the original floats via shuffle reduce.
__global__ __launch_bounds__(256) void prep_kernel(
    const float* __restrict__ X, const float* __restrict__ Mx,
    unsigned char* __restrict__ Xq, unsigned char* __restrict__ Mq,
    float* __restrict__ xsq, float* __restrict__ msq)
{
    const int lane = threadIdx.x & 63;
    const int row  = blockIdx.x * 4 + (threadIdx.x >> 6);

    const float* src; unsigned char* dst; float* sq;
    if (row < B_DIM) {
        src = X + (size_t)row * D_DIM; dst = Xq + (size_t)row * D_DIM; sq = xsq + row;
    } else {
        const int r = row - B_DIM;
        src = Mx + (size_t)r * D_DIM; dst = Mq + (size_t)r * D_DIM; sq = msq + r;
    }

    const float4* s4 = (const float4*)src;
    uc8* d8 = (uc8*)dst;
    float acc = 0.f;
    for (int i = lane; i < D_DIM / 8; i += 64) {
        float4 a = s4[2 * i], b = s4[2 * i + 1];
        acc += a.x * a.x + a.y * a.y + a.z * a.z + a.w * a.w;
        acc += b.x * b.x + b.y * b.y + b.z * b.z + b.w * b.w;
        uc8 q;
        q.c[0] = (unsigned char)__float2int_rn(a.x * QSCALE);
        q.c[1] = (unsigned char)__float2int_rn(a.y * QSCALE);
        q.c[2] = (unsigned char)__float2int_rn(a.z * QSCALE);
        q.c[3] = (unsigned char)__float2int_rn(a.w * QSCALE);
        q.c[4] = (unsigned char)__float2int_rn(b.x * QSCALE);
        q.c[5] = (unsigned char)__float2int_rn(b.y * QSCALE);
        q.c[6] = (unsigned char)__float2int_rn(b.z * QSCALE);
        q.c[7] = (unsigned char)__float2int_rn(b.w * QSCALE);
        d8[i] = q;
    }
    #pragma unroll
    for (int off = 32; off > 0; off >>= 1)
        acc += __shfl_down(acc, off, 64);
    if (lane == 0) *sq = acc;
}

// ---------------------------------------------------------------------------
// global -> LDS direct (async) load, 16 B per lane; dest = wave-uniform base +
// lane*16, i.e. one issue fills 1024 contiguous LDS bytes (16 rows x 64 B).
__device__ __forceinline__ void gld_lds16(const unsigned char* g, unsigned char* l) {
    __builtin_amdgcn_global_load_lds(
        (const __attribute__((address_space(1))) unsigned int*)g,
        (__attribute__((address_space(3))) unsigned int*)l,
        16, 0, 0);
}

// ---------------------------------------------------------------------------
// C[row,col] = (2*cross - xsq[row] - msq[col]) / 500, cross = acc_i32/127^2.
// A: [4096, 2496] u8 row-major; Bt: [2048, 2496] u8 row-major (NT GEMM).
//
// LDS layout: chunks of 16 rows x 64 k-bytes (1024 B, one gld_lds16 each).
// Chunk index = rowblock*3 + kseg; within chunk: row_local*64 + byte.
// As: 4 rowblocks (64 rows) = 12 chunks; Bs: 8 rowblocks (128) = 24 chunks.
__global__ __launch_bounds__(128, 2) void gemm_kernel(
    const unsigned char* __restrict__ A,
    const unsigned char* __restrict__ Bt,
    const float* __restrict__ xsq, const float* __restrict__ msq,
    float* __restrict__ C)
{
    constexpr int N = S_DIM;
    constexpr int K = D_DIM;   // bytes per row

    __shared__ __align__(16) unsigned char As[BM * BK];  // 12 KB
    __shared__ __align__(16) unsigned char Bs[BN * BK];  // 24 KB

    const int lane = threadIdx.x & 63;
    const int w    = threadIdx.x >> 6;   // 2 waves; wave w owns cols w*64..+63
    const int bm = blockIdx.y;
    const int bn = blockIdx.x;

    // Staging (18 gld_lds16/wave/iter): wave w stages A rowblocks {2w,2w+1}
    // and B rowblocks {4w..4w+3}, 3 ksegs each.
    const int srow  = lane >> 2;          // row within 16-row chunk
    const int sbyte = (lane & 3) * 16;    // byte within 64-B k-window
    const unsigned char* gA = A  + (size_t)(bm * BM + w * 32 + srow) * K + sbyte;
    const unsigned char* gB = Bt + (size_t)(bn * BN + w * 64 + srow) * K + sbyte;

    int4v acc[4][4] = {};

    // i8 16x16x64 A/B fragment (R5-verified): m (or n) = lane&15,
    // k-byte = (lane>>4)*16 + j. One ds_read_b128 per fragment.
    const int ko = (lane >> 4) * 16;
    const int fr = lane & 15;

    for (int t = 0; t < KITERS; ++t) {   // 13 iterations
        __syncthreads();   // previous tile fully consumed
        #pragma unroll
        for (int c = 0; c < 3; ++c) {
            gld_lds16(gA + c * 64,                  &As[(((w * 2    ) * 3) + c) * 1024]);
            gld_lds16(gA + (size_t)16 * K + c * 64, &As[(((w * 2 + 1) * 3) + c) * 1024]);
            gld_lds16(gB + c * 64,                  &Bs[(((w * 4    ) * 3) + c) * 1024]);
            gld_lds16(gB + (size_t)16 * K + c * 64, &Bs[(((w * 4 + 1) * 3) + c) * 1024]);
            gld_lds16(gB + (size_t)32 * K + c * 64, &Bs[(((w * 4 + 2) * 3) + c) * 1024]);
            gld_lds16(gB + (size_t)48 * K + c * 64, &Bs[(((w * 4 + 3) * 3) + c) * 1024]);
        }
        gA += BK; gB += BK;
        __syncthreads();   // drains vmcnt(0); 13 drains total

        #pragma unroll
        for (int s = 0; s < 3; ++s) {    // three 64-byte k-steps
            int4v af[4], bfr[4];
            #pragma unroll
            for (int i = 0; i < 4; ++i) {
                af[i]  = *(const int4v*)&As[((i          * 3) + s) * 1024 + fr * 64 + ko];
                bfr[i] = *(const int4v*)&Bs[(((w * 4 + i) * 3) + s) * 1024 + fr * 64 + ko];
            }
            #pragma unroll
            for (int mi = 0; mi < 4; ++mi)
                #pragma unroll
                for (int ni = 0; ni < 4; ++ni)
                    acc[mi][ni] = __builtin_amdgcn_mfma_i32_16x16x64_i8(
                        af[mi], bfr[ni], acc[mi][ni], 0, 0, 0);
        }
    }

    // Epilogue. C/D layout dtype-independent (m121-m128): col = lane&15,
    // row = (lane>>4)*4 + reg. cross = acc/127^2 in fp32.
    const int row0 = bm * BM + (lane >> 4) * 4;
    const int col0 = bn * BN + w * 64 + fr;
    float ms[4];
    #pragma unroll
    for (int ni = 0; ni < 4; ++ni) ms[ni] = msq[col0 + ni * 16];
    #pragma unroll
    for (int mi = 0; mi < 4; ++mi) {
        #pragma unroll
        for (int r = 0; r < 4; ++r) {
            const int row = row0 + mi * 16 + r;
            const float xs = xsq[row];
            #pragma unroll
            for (int ni = 0; ni < 4; ++ni) {
                const float cr2 = (float)acc[mi][ni][r] * (2.0f / QSCALE2);
                const float v = (cr2 - xs - ms[ni]) * (1.0f / 500.0f);
                C[(size_t)row * N + col0 + ni * 16] = v;
            }
        }
    }
}

// ---------------------------------------------------------------------------
extern "C" void kernel_launch(void* const* d_in, const int* in_sizes, int n_in,
                              void* d_out, int out_size, void* d_ws, size_t ws_size,
                              hipStream_t stream) {
    const float* X  = (const float*)d_in[0];  // [4096, 2496]
    const float* Mx = (const float*)d_in[1];  // [2048, 2496]
    float* out = (float*)d_out;               // [4096, 2048]

    // Workspace layout (~15.4 MB): Xq u8 | Mq u8 | xsq f32 | msq f32
    unsigned char* Xq = (unsigned char*)d_ws;
    unsigned char* Mq = Xq + (size_t)B_DIM * D_DIM;
    float* xsq = (float*)(Mq + (size_t)S_DIM * D_DIM);
    float* msq = xsq + B_DIM;

    prep_kernel<<<(B_DIM + S_DIM) / 4, 256, 0, stream>>>(X, Mx, Xq, Mq, xsq, msq);

    dim3 grid(S_DIM / BN, B_DIM / BM);  // (16, 64) = 1024 blocks -> 4/CU
    gemm_kernel<<<grid, 128, 0, stream>>>(Xq, Mq, xsq, msq, out);
}